// Round 4
// baseline (121.398 us; speedup 1.0000x reference)
//
#include <hip/hip_runtime.h>

typedef __attribute__((ext_vector_type(8))) __bf16 bf16x8;
typedef __attribute__((ext_vector_type(8))) unsigned short u16x8;
typedef __attribute__((ext_vector_type(4))) unsigned short u16x4;
typedef __attribute__((ext_vector_type(4))) float f32x4;

__device__ __forceinline__ f32x4 mfma16(bf16x8 a, bf16x8 b, f32x4 c) {
  return __builtin_amdgcn_mfma_f32_16x16x32_bf16(a, b, c, 0, 0, 0);
}

__device__ __forceinline__ bf16x8 cvt8(f32x4 a, f32x4 b) {
  bf16x8 r;
  r[0] = (__bf16)a[0]; r[1] = (__bf16)a[1]; r[2] = (__bf16)a[2]; r[3] = (__bf16)a[3];
  r[4] = (__bf16)b[0]; r[5] = (__bf16)b[1]; r[6] = (__bf16)b[2]; r[7] = (__bf16)b[3];
  return r;
}

__device__ __forceinline__ unsigned short bf1(float f) {
  return __builtin_bit_cast(unsigned short, (__bf16)f);
}

__device__ __forceinline__ bf16x8 ld_frag(const unsigned short* p) {
  return __builtin_bit_cast(bf16x8, *(const u16x8*)p);
}

// ---------------------------------------------------------------------------
// kprep: blocks 0..31 -> BwF frags, 32..63 -> CwF frags, block 64 -> A powers
// (akbF frags), sigma_max(A), dflag, norm_out=0.
//   BwF g=(kstep*4+nt)*64+l : Bw[n=nt*16+(l&15)][k=kstep*32+(l>>4)*8 ..+7]
//   CwF g=(dt*2+kk)*64+l    : Cw[d=dt*16+(l&15)][n=kk*32+(l>>4)*8 ..+7]
//   akbF g=((kp*2+kk)*4+nt)*64+l : A^{kp+1}[n=nt*16+(l&15)][m=kk*32+(l>>4)*8..]
// ---------------------------------------------------------------------------
__global__ __launch_bounds__(256) void kprep(const float* __restrict__ Bw,
                                             const float* __restrict__ Cw,
                                             const float* __restrict__ Al,
                                             const float* __restrict__ Ah,
                                             const float* __restrict__ Dv,
                                             unsigned short* __restrict__ BwF,
                                             unsigned short* __restrict__ CwF,
                                             unsigned short* __restrict__ akbF,
                                             float* __restrict__ dflag,
                                             float* __restrict__ spec,
                                             float* __restrict__ norm_out) {
  const int bid = blockIdx.x, tid = threadIdx.x;
  if (bid < 32) {
    int g = bid * 256 + tid;
    int kstep = g >> 8, nt = (g >> 6) & 3, ln = g & 63;
    int n = nt * 16 + (ln & 15);
    int k = kstep * 32 + (ln >> 4) * 8;
    f32x4 a = *(const f32x4*)&Bw[(size_t)n * 1024 + k];
    f32x4 b = *(const f32x4*)&Bw[(size_t)n * 1024 + k + 4];
    *(u16x8*)&BwF[(size_t)g * 8] = __builtin_bit_cast(u16x8, cvt8(a, b));
    return;
  }
  if (bid < 64) {
    int g = (bid - 32) * 256 + tid;
    int dt = g >> 7, kk = (g >> 6) & 1, ln = g & 63;
    int d = dt * 16 + (ln & 15);
    int n = kk * 32 + (ln >> 4) * 8;
    f32x4 a = *(const f32x4*)&Cw[(size_t)d * 64 + n];
    f32x4 b = *(const f32x4*)&Cw[(size_t)d * 64 + n + 4];
    *(u16x8*)&CwF[(size_t)g * 8] = __builtin_bit_cast(u16x8, cvt8(a, b));
    return;
  }
  // --- block 64: A = Al@Ah, powers, sigma, dflag, norm zero ---
  __shared__ float A[4][64][68];
  __shared__ float Alo[64][36];
  __shared__ float Ahi[32][68];
  const int lane = tid & 63, wq = tid >> 6;
  for (int f = tid; f < 512; f += 256) {
    int r = f >> 3, c = (f & 7) << 2;
    *(f32x4*)&Alo[r][c] = *(const f32x4*)&Al[r * 32 + c];
  }
  for (int f = tid; f < 512; f += 256) {
    int r = f >> 4, c = (f & 15) << 2;
    *(f32x4*)&Ahi[r][c] = *(const f32x4*)&Ah[r * 64 + c];
  }
  if (tid == 0) *norm_out = 0.0f;
  __syncthreads();
  {
    float ar[32];
#pragma unroll
    for (int r = 0; r < 32; r++) ar[r] = Alo[lane][r];
#pragma unroll
    for (int m4 = 0; m4 < 4; m4++) {
      f32x4 s = {0.f, 0.f, 0.f, 0.f};
#pragma unroll
      for (int r = 0; r < 32; r++)
        s += ar[r] * *(const f32x4*)&Ahi[r][wq * 16 + m4 * 4];
      *(f32x4*)&A[0][lane][wq * 16 + m4 * 4] = s;
    }
  }
  __syncthreads();
  for (int p = 1; p < 4; p++) {
    float ar[64];
#pragma unroll
    for (int k = 0; k < 64; k++) ar[k] = A[p - 1][lane][k];
#pragma unroll
    for (int m4 = 0; m4 < 4; m4++) {
      f32x4 s = {0.f, 0.f, 0.f, 0.f};
#pragma unroll
      for (int k = 0; k < 64; k++)
        s += ar[k] * *(const f32x4*)&A[0][k][wq * 16 + m4 * 4];
      *(f32x4*)&A[p][lane][wq * 16 + m4 * 4] = s;
    }
    __syncthreads();
  }
#pragma unroll
  for (int i = 0; i < 8; i++) {
    int e = tid + 256 * i;
    int kp = e >> 9, kk = (e >> 8) & 1, nt = (e >> 6) & 3, ln = e & 63;
    int n = nt * 16 + (ln & 15);
    int mc = kk * 32 + (ln >> 4) * 8;
    f32x4 a = *(const f32x4*)&A[kp][n][mc];
    f32x4 b = *(const f32x4*)&A[kp][n][mc + 4];
    *(u16x8*)&akbF[(size_t)e * 8] = __builtin_bit_cast(u16x8, cvt8(a, b));
  }
  if (wq == 0) {   // power iteration on A^T A
    float ar[64], at[64];
#pragma unroll
    for (int m = 0; m < 64; m++) { ar[m] = A[0][lane][m]; at[m] = A[0][m][lane]; }
    float v = 1.0f + 0.001f * (float)lane;
    for (int it = 0; it < 8; it++) {
      float w = 0.f;
#pragma unroll
      for (int m = 0; m < 64; m++) w += ar[m] * __shfl(v, m, 64);
      float z = 0.f;
#pragma unroll
      for (int m = 0; m < 64; m++) z += at[m] * __shfl(w, m, 64);
      float ss = z * z;
#pragma unroll
      for (int off = 32; off; off >>= 1) ss += __shfl_xor(ss, off, 64);
      v = z * rsqrtf(ss + 1e-38f);
    }
    float w = 0.f;
#pragma unroll
    for (int m = 0; m < 64; m++) w += ar[m] * __shfl(v, m, 64);
    float ss = w * w;
#pragma unroll
    for (int off = 32; off; off >>= 1) ss += __shfl_xor(ss, off, 64);
    if (lane == 0) *spec = sqrtf(ss);
  }
  if (wq == 1) {
    float dm = 0.f;
#pragma unroll
    for (int i = 0; i < 16; i++) dm = fmaxf(dm, fabsf(Dv[lane + i * 64]));
#pragma unroll
    for (int off = 32; off; off >>= 1) dm = fmaxf(dm, __shfl_xor(dm, off, 64));
    if (lane == 0) *dflag = dm;
  }
}

// ---------------------------------------------------------------------------
// G1 (split-K x4): u[t][n] = (x·Bw^T + Bb)[t][n] * rw[t]
// 8 waves/block: rt = wid&1 (two 16-row tiles), kh = wid>>1 (K quarter).
// 1024 blocks x 8 waves = 8192 waves = 32/CU. LDS reduce of 3 partials.
// ---------------------------------------------------------------------------
__global__ __launch_bounds__(512) void g1_gemm(const float* __restrict__ x,
                                               const unsigned short* __restrict__ BwF,
                                               const float* __restrict__ Bb,
                                               const float* __restrict__ rw,
                                               float* __restrict__ u) {
  __shared__ f32x4 accS[3][2][4][64];
  const int tid = threadIdx.x, lane = tid & 63, wid = tid >> 6;
  const int rt = wid & 1, kh = wid >> 1;
  const int t0 = blockIdx.x * 32 + rt * 16;
  const int trow = t0 + (lane & 15);
  const int q8 = (lane >> 4) * 8;
  f32x4 acc[4];
#pragma unroll
  for (int nt = 0; nt < 4; nt++) acc[nt] = f32x4{0.f, 0.f, 0.f, 0.f};
  const int ks0 = kh * 8;
#pragma unroll 4
  for (int ks = ks0; ks < ks0 + 8; ks++) {
    const float* xp = &x[(size_t)trow * 1024 + ks * 32 + q8];
    bf16x8 b = cvt8(*(const f32x4*)xp, *(const f32x4*)(xp + 4));
#pragma unroll
    for (int nt = 0; nt < 4; nt++) {
      bf16x8 a = ld_frag(&BwF[((size_t)(ks * 4 + nt) * 64 + lane) * 8]);
      acc[nt] = mfma16(a, b, acc[nt]);
    }
  }
  if (kh != 0) {
#pragma unroll
    for (int nt = 0; nt < 4; nt++) accS[kh - 1][rt][nt][lane] = acc[nt];
  }
  __syncthreads();
  if (kh == 0) {
    const float rwt = rw[trow];
#pragma unroll
    for (int nt = 0; nt < 4; nt++) {
      acc[nt] += accS[0][rt][nt][lane];
      acc[nt] += accS[1][rt][nt][lane];
      acc[nt] += accS[2][rt][nt][lane];
      int n0 = nt * 16 + (lane >> 4) * 4;
      f32x4 bb = *(const f32x4*)&Bb[n0];
      f32x4 o;
#pragma unroll
      for (int j = 0; j < 4; j++) o[j] = (acc[nt][j] + bb[j]) * rwt;
      *(f32x4*)&u[(size_t)trow * 64 + n0] = o;
    }
  }
}

// ---------------------------------------------------------------------------
// K2G2 fused: block = 4 waves = ONE 16-row t-tile.
// Phase 1 (duplicated in all 4 waves; u reads hit L1): hs = u + sum A^k u_{t-k}
//   + batch-end state-norm (wave 0 only). Per-wave LDS transpose (no barrier).
// Phase 2: the 16 d-chunks split across waves (dc = wid*4 ..+3).
// 2048 blocks x 4 waves = 8192 waves = 32/CU.
// ---------------------------------------------------------------------------
__global__ __launch_bounds__(256) void k2g2(const float* __restrict__ u,
                                            const unsigned short* __restrict__ akbF,
                                            const unsigned short* __restrict__ CwF,
                                            const float* __restrict__ Cb,
                                            const float* __restrict__ Dv,
                                            const float* __restrict__ x,
                                            const float* __restrict__ dflag,
                                            float* __restrict__ out,
                                            float* __restrict__ norm_out) {
  __shared__ unsigned short hsT[4][16][80];
  const int tid = threadIdx.x, lane = tid & 63, wid = tid >> 6;
  const int t0 = blockIdx.x * 16;
  const int bstart = t0 & ~4095;
  const int trow = t0 + (lane & 15);
  const int q8 = (lane >> 4) * 8;
  f32x4 acc[4];
#pragma unroll
  for (int nt = 0; nt < 4; nt++) acc[nt] = f32x4{0.f, 0.f, 0.f, 0.f};
#pragma unroll
  for (int kp = 0; kp < 4; kp++) {
    int g = trow - (kp + 1);
#pragma unroll
    for (int kk = 0; kk < 2; kk++) {
      f32x4 xa = {0.f, 0.f, 0.f, 0.f}, xb = {0.f, 0.f, 0.f, 0.f};
      if (g >= bstart) {
        const float* up = &u[(size_t)g * 64 + kk * 32 + q8];
        xa = *(const f32x4*)up;
        xb = *(const f32x4*)(up + 4);
      }
      bf16x8 b = cvt8(xa, xb);
#pragma unroll
      for (int nt = 0; nt < 4; nt++) {
        bf16x8 a = ld_frag(&akbF[(size_t)(((kp * 2 + kk) * 4 + nt) * 64 + lane) * 8]);
        acc[nt] = mfma16(a, b, acc[nt]);
      }
    }
  }
  // identity (f32) + pack hs to per-wave LDS + batch-end norm (wave 0)
  const bool bnorm = (wid == 0) && (((t0 + 15) & 4095) == 4095);
  float ss = 0.f;
#pragma unroll
  for (int nt = 0; nt < 4; nt++) {
    int n0 = nt * 16 + (lane >> 4) * 4;
    f32x4 uid = *(const f32x4*)&u[(size_t)trow * 64 + n0];
    u16x4 pk;
#pragma unroll
    for (int j = 0; j < 4; j++) {
      float val = acc[nt][j] + uid[j];
      pk[j] = bf1(val);
      if (bnorm && (lane & 15) == 15) ss += val * val;
    }
    *(u16x4*)&hsT[wid][lane & 15][n0] = pk;
  }
  if (bnorm && (lane & 15) == 15) {
    ss += __shfl_xor(ss, 16, 64);
    ss += __shfl_xor(ss, 32, 64);
    if (lane == 15) atomicAdd(norm_out, sqrtf(ss) * 0.125f);
  }
  // hs B-frags (col=t=lane&15, k=n)
  bf16x8 hf[2];
#pragma unroll
  for (int kk = 0; kk < 2; kk++)
    hf[kk] = ld_frag(&hsT[wid][lane & 15][kk * 32 + q8]);
  const bool hasD = (*dflag != 0.0f);
  const size_t xrow = (size_t)trow * 1024;
#pragma unroll 2
  for (int dc = wid * 4; dc < wid * 4 + 4; dc++) {
    const int d0 = dc * 64;
    f32x4 o[4];
#pragma unroll
    for (int dt = 0; dt < 4; dt++) o[dt] = f32x4{0.f, 0.f, 0.f, 0.f};
#pragma unroll
    for (int kk = 0; kk < 2; kk++)
#pragma unroll
      for (int dt = 0; dt < 4; dt++) {
        bf16x8 a = ld_frag(&CwF[(size_t)((((d0 >> 4) + dt) * 2 + kk) * 64 + lane) * 8]);
        o[dt] = mfma16(a, hf[kk], o[dt]);
      }
#pragma unroll
    for (int dt = 0; dt < 4; dt++) {
      int db = d0 + dt * 16 + (lane >> 4) * 4;
      f32x4 cb = *(const f32x4*)&Cb[db];
      f32x4 v = o[dt] + cb;
      if (hasD) {
        f32x4 dd = *(const f32x4*)&Dv[db];
        f32x4 xv = *(const f32x4*)&x[xrow + db];
        v += dd * xv;
      }
      *(f32x4*)&out[xrow + db] = v;
    }
  }
}

extern "C" void kernel_launch(void* const* d_in, const int* in_sizes, int n_in,
                              void* d_out, int out_size, void* d_ws, size_t ws_size,
                              hipStream_t stream) {
  const float* x  = (const float*)d_in[0];
  const float* rw = (const float*)d_in[1];
  const float* Al = (const float*)d_in[2];
  const float* Ah = (const float*)d_in[3];
  const float* Bw = (const float*)d_in[4];
  const float* Bb = (const float*)d_in[5];
  const float* Cw = (const float*)d_in[6];
  const float* Cb = (const float*)d_in[7];
  const float* Dv = (const float*)d_in[8];
  float* out = (float*)d_out;

  char* ws = (char*)d_ws;
  unsigned short* akbF  = (unsigned short*)(ws);            // 32 KiB
  float*          dflag = (float*)(ws + 32768);             // 4 B
  unsigned short* BwF   = (unsigned short*)(ws + 65536);    // 128 KiB
  unsigned short* CwF   = (unsigned short*)(ws + 196608);   // 128 KiB
  float*          u     = (float*)(ws + 327680);            // 8 MiB

  float* norm_out = out + (out_size - 2);
  float* spec_out = out + (out_size - 1);

  kprep<<<dim3(65), dim3(256), 0, stream>>>(Bw, Cw, Al, Ah, Dv, BwF, CwF, akbF,
                                            dflag, spec_out, norm_out);
  g1_gemm<<<dim3(1024), dim3(512), 0, stream>>>(x, BwF, Bb, rw, u);
  k2g2<<<dim3(2048), dim3(256), 0, stream>>>(u, akbF, CwF, Cb, Dv, x, dflag, out,
                                             norm_out);
}